// Round 9
// baseline (171.334 us; speedup 1.0000x reference)
//
#include <hip/hip_runtime.h>
#include <hip/hip_bf16.h>
#include <stdint.h>

typedef short v8s __attribute__((ext_vector_type(8)));
typedef float v4f __attribute__((ext_vector_type(4)));
typedef float v16f __attribute__((ext_vector_type(16)));

#define N_EMBD 1024
#define HEAD 128
#define TOKENS 16384   // 8*2048
#define T_SEQ 2048
#define BATCH 8
#define BPB 136        // attn blocks/batch: sum_{qt2=0}^{15} (qt2+1)  [2-kt splits]

__device__ __forceinline__ short f2bf(float f) {
    union { float f; uint32_t u; } c; c.f = f;
    uint32_t u = c.u;
    uint32_t r = (u + 0x7fffu + ((u >> 16) & 1u)) >> 16;
    return (short)r;
}

__device__ __forceinline__ float bf2f(short s) {
    union { uint32_t u; float f; } c; c.u = ((uint32_t)(uint16_t)s) << 16;
    return c.f;
}

// ---------------- kernel 1: fused pack (x -> xpk, W -> wpk) ----------------
// blocks 0..1023:  x -> bf16 in MFMA A-fragment order (LDS-staged, both sides
//                  coalesced). chunk (rb,kb) = 64 lanes x 8 shorts;
//                  tok = rb*32+(l&31), k = kb*16+(l>>5)*8+j.
// blocks 1024..2559: W -> bf16 in B-fragment order.
__global__ __launch_bounds__(256)
void pack_kernel(const float* __restrict__ x,
                 const float* __restrict__ Wq, const float* __restrict__ Wk,
                 const float* __restrict__ Wv,
                 short* __restrict__ xpk, short* __restrict__ wpk) {
    const int blk = blockIdx.x;
    const int t   = threadIdx.x;
    if (blk < 1024) {
        const int rb = blk >> 1;          // 0..511
        const int kh = blk & 1;           // k-half (512 k each)
        __shared__ short sX[32 * 520];    // [tok][k_local], pad to 520

        for (int it = 0; it < 8; ++it) {
            int idx = it * 256 + t;       // 2048 = 32 tok * 64 octets
            int tok = idx >> 6, ko = idx & 63;
            const float* src = x + (size_t)(rb * 32 + tok) * 1024 + kh * 512 + ko * 8;
            float4 lo = *(const float4*)(src);
            float4 hi = *(const float4*)(src + 4);
            union { short s[8]; uint4 u; } p;
            p.s[0] = f2bf(lo.x); p.s[1] = f2bf(lo.y); p.s[2] = f2bf(lo.z); p.s[3] = f2bf(lo.w);
            p.s[4] = f2bf(hi.x); p.s[5] = f2bf(hi.y); p.s[6] = f2bf(hi.z); p.s[7] = f2bf(hi.w);
            *(uint4*)(&sX[tok * 520 + ko * 8]) = p.u;
        }
        __syncthreads();

        for (int it = 0; it < 8; ++it) {
            int kb_loc = it * 4 + (t >> 6);   // 0..31
            int l = t & 63;
            uint4 d = *(const uint4*)(&sX[(l & 31) * 520 + kb_loc * 16 + (l >> 5) * 8]);
            int kb = kh * 32 + kb_loc;
            *(uint4*)(&xpk[(((size_t)rb * 64 + kb) * 64 + l) * 8]) = d;
        }
    } else {
        int tid = (blk - 1024) * 256 + t;
        int w   = tid >> 17;
        int rem = tid & 131071;               // c*128 + h
        int c = rem >> 7, h = rem & 127;
        const float* src = (w == 0) ? Wq : ((w == 1) ? Wk : Wv);
        int cb = h >> 5, kb = c >> 4;
        int l  = (h & 31) | (((c >> 3) & 1) << 5);
        wpk[((((w * 4 + cb) * 64) + kb) * 64 + l) * 8 + (c & 7)] = f2bf(src[rem]);
    }
}

// ---------------- kernel 2: QKV GEMM, packed-fragment streaming ----------------
// Main loop: zero LDS / zero barriers / depth-2 named-register prefetch.
// Epilogues: w==0 -> qb rows; w==1 -> K in attn-A-fragment chunks (kpk);
// w==2 -> V^T in attn-A-fragment chunks (vpk).
__global__ __launch_bounds__(256)
void qkv_gemm(const short* __restrict__ xpk, const short* __restrict__ wpk,
              short* __restrict__ qkv, short* __restrict__ kpk,
              short* __restrict__ vpk) {
    const int bid = blockIdx.x;
    const int xcd = bid & 7, q = bid >> 3;
    const int mt  = xcd * 32 + q / 3;
    const int w   = q % 3;
    const int m0  = mt * 64;

    __shared__ short sT[128 * 72];   // epilogue staging (K path uses 64x136)

    const int t = threadIdx.x;
    const int lane = t & 63, wv = t >> 6;
    const int l31 = lane & 31, l1 = lane >> 5;
    const int wm = wv & 1, wn = wv >> 1;

    const int rb = mt * 2 + wm;                       // A row-block (32 rows)
    const short* ap  = xpk + (size_t)rb * 32768 + lane * 8;            // + kb*512
    const short* bp0 = wpk + (size_t)(w * 4 + 2 * wn) * 32768 + lane * 8;
    const short* bp1 = wpk + (size_t)(w * 4 + 2 * wn + 1) * 32768 + lane * 8;

    v16f acc[2];
    for (int i = 0; i < 16; ++i) { acc[0][i] = 0.f; acc[1][i] = 0.f; }

    v8s A0k0, A0k1, A1k0, A1k1;
    v8s B0k0n0, B0k0n1, B0k1n0, B0k1n1, B1k0n0, B1k0n1, B1k1n0, B1k1n1;

#define LOADSET0(IT) do { int o_ = (IT) * 1024;                                  \
        A0k0   = *(const v8s*)(ap  + o_);                                        \
        A0k1   = *(const v8s*)(ap  + o_ + 512);                                  \
        B0k0n0 = *(const v8s*)(bp0 + o_);                                        \
        B0k0n1 = *(const v8s*)(bp1 + o_);                                        \
        B0k1n0 = *(const v8s*)(bp0 + o_ + 512);                                  \
        B0k1n1 = *(const v8s*)(bp1 + o_ + 512);                                  \
    } while (0)

#define LOADSET1(IT) do { int o_ = (IT) * 1024;                                  \
        A1k0   = *(const v8s*)(ap  + o_);                                        \
        A1k1   = *(const v8s*)(ap  + o_ + 512);                                  \
        B1k0n0 = *(const v8s*)(bp0 + o_);                                        \
        B1k0n1 = *(const v8s*)(bp1 + o_);                                        \
        B1k1n0 = *(const v8s*)(bp0 + o_ + 512);                                  \
        B1k1n1 = *(const v8s*)(bp1 + o_ + 512);                                  \
    } while (0)

#define COMPUTE0() do {                                                          \
        acc[0] = __builtin_amdgcn_mfma_f32_32x32x16_bf16(A0k0, B0k0n0, acc[0], 0, 0, 0); \
        acc[1] = __builtin_amdgcn_mfma_f32_32x32x16_bf16(A0k0, B0k0n1, acc[1], 0, 0, 0); \
        acc[0] = __builtin_amdgcn_mfma_f32_32x32x16_bf16(A0k1, B0k1n0, acc[0], 0, 0, 0); \
        acc[1] = __builtin_amdgcn_mfma_f32_32x32x16_bf16(A0k1, B0k1n1, acc[1], 0, 0, 0); \
    } while (0)

#define COMPUTE1() do {                                                          \
        acc[0] = __builtin_amdgcn_mfma_f32_32x32x16_bf16(A1k0, B1k0n0, acc[0], 0, 0, 0); \
        acc[1] = __builtin_amdgcn_mfma_f32_32x32x16_bf16(A1k0, B1k0n1, acc[1], 0, 0, 0); \
        acc[0] = __builtin_amdgcn_mfma_f32_32x32x16_bf16(A1k1, B1k1n0, acc[0], 0, 0, 0); \
        acc[1] = __builtin_amdgcn_mfma_f32_32x32x16_bf16(A1k1, B1k1n1, acc[1], 0, 0, 0); \
    } while (0)

    LOADSET0(0);
    LOADSET1(1);
    for (int it = 0; it < 32; it += 2) {
        COMPUTE0();
        if (it + 2 < 32) LOADSET0(it + 2);
        COMPUTE1();
        if (it + 3 < 32) LOADSET1(it + 3);
    }

#undef LOADSET0
#undef LOADSET1
#undef COMPUTE0
#undef COMPUTE1

    // epilogues. 32x32 C-layout: col = lane&31, row m = (reg&3) + 8*(reg>>2) + 4*l1
    const int b_  = m0 >> 11;
    const int kt_ = (m0 >> 6) & 31;
    if (w == 0) {
        for (int ni = 0; ni < 2; ++ni) {
            int col = wn * 64 + ni * 32 + l31;
            for (int reg = 0; reg < 16; ++reg) {
                int m = (reg & 3) + 8 * (reg >> 2) + 4 * l1;
                qkv[(size_t)(m0 + wm * 32 + m) * HEAD + col] = f2bf(acc[ni][reg]);
            }
        }
    } else if (w == 1) {
        // stage [token][head] stride 136, then emit attn A-fragment chunks
        for (int ni = 0; ni < 2; ++ni) {
            int col = wn * 64 + ni * 32 + l31;
            for (int reg = 0; reg < 16; ++reg) {
                int m = (reg & 3) + 8 * (reg >> 2) + 4 * l1;
                sT[(wm * 32 + m) * 136 + col] = f2bf(acc[ni][reg]);
            }
        }
        __syncthreads();
        short* kdst = kpk + ((size_t)(b_ * 32 + kt_) * 16) * 512;
        for (int it = 0; it < 4; ++it) {
            int c = it * 256 + t;
            int chunk = c >> 6, l = c & 63;        // chunk = ni*4 + ks
            int ni2 = chunk >> 2, ks = chunk & 3;
            uint4 d = *(const uint4*)(&sT[(ni2 * 16 + (l & 15)) * 136 + ks * 32 + (l >> 4) * 8]);
            *(uint4*)(&kdst[chunk * 512 + l * 8]) = d;
        }
    } else {
        // stage V^T [d][token] stride 72, then emit attn A-fragment chunks
        for (int ni = 0; ni < 2; ++ni) {
            int col = wn * 64 + ni * 32 + l31;
            for (int g = 0; g < 4; ++g) {
                union { short s[4]; uint64_t u; } pk;
                for (int r = 0; r < 4; ++r) pk.s[r] = f2bf(acc[ni][g * 4 + r]);
                *(uint64_t*)(&sT[col * 72 + wm * 32 + 8 * g + 4 * l1]) = pk.u;
            }
        }
        __syncthreads();
        short* vdst = vpk + ((size_t)(b_ * 32 + kt_) * 16) * 512;
        for (int it = 0; it < 4; ++it) {
            int c = it * 256 + t;
            int chunk = c >> 6, l = c & 63;        // chunk = oni*2 + kk2
            int oni = chunk >> 1, kk2 = chunk & 1;
            uint4 d = *(const uint4*)(&sT[(oni * 16 + (l & 15)) * 72 + kk2 * 32 + (l >> 4) * 8]);
            *(uint4*)(&vdst[chunk * 512 + l * 8]) = d;
        }
    }
}

// ---------------- kernel 3: flash attention, barrier-free fragment streaming ----
// 2-kt splits (exactly 2 tiles per split, uniform blocks): grid 1088 = 4.25
// blocks/CU (VGPR 124 -> 4 resident = +33% waves vs 3-kt's 768-block grid).
// Zero s_barrier; K/V fragments direct global->VGPR (coalesced 1KB wave-loads);
// only P through LDS, same-wave write/read (lgkmcnt ordering).
__global__ __launch_bounds__(256)
void attn_kernel(const short* __restrict__ qb, const short* __restrict__ kpk,
                 const short* __restrict__ vpk, short* __restrict__ po,
                 float* __restrict__ pl) {
    const int bid = blockIdx.x;
    const int b  = bid & 7;
    const int r0 = bid >> 3;        // 0..135
    int qt2 = 0, c0 = 0;
    for (;;) { int sz = qt2 + 1; if (r0 < c0 + sz) break; c0 += sz; ++qt2; }
    const int s = r0 - c0;
    const int q0 = qt2 * 128;
    const int nkt = 2 * qt2 + 2;
    const int kt0 = s * 2;
    const int kt1 = (kt0 + 2 < nkt) ? (kt0 + 2) : nkt;

    __shared__ short sP[128 * 72];    // P [qrow][key], stride 72 (per-wave rows)

    const int t = threadIdx.x;
    const int wv = t >> 6, lane = t & 63, ln = lane & 15, qd = lane >> 4;
    const int wrow0 = q0 + wv * 32;

    v8s qf[2][4];
    for (int qg = 0; qg < 2; ++qg) {
        const short* qrow = qb + ((size_t)(b * T_SEQ + wrow0 + qg * 16 + ln)) * HEAD;
        for (int ks = 0; ks < 4; ++ks)
            qf[qg][ks] = *(const v8s*)(qrow + ks * 32 + qd * 8);
    }

    v4f o[2][8] = {};
    float rs[2] = {0.f, 0.f};
    const float sc = 1.4426950408889634f / 11.313708498984761f;  // log2e / sqrt(128)

    const short* kbB = kpk + ((size_t)b * 32 * 16) * 512 + lane * 8;
    const short* vbB = vpk + ((size_t)b * 32 * 16) * 512 + lane * 8;

    for (int kt = kt0; kt < kt1; ++kt) {
        if (kt * 64 >= wrow0 + 32) break;   // fully masked from here on
        const short* kc = kbB + (size_t)kt * 8192;
        const short* vc = vbB + (size_t)kt * 8192;

        // S^T: A = K fragments (direct), B = Q fragments
        v4f st[2][4] = {};
#pragma unroll
        for (int ni = 0; ni < 4; ++ni) {
            v8s kf0 = *(const v8s*)(kc + (ni * 4 + 0) * 512);
            v8s kf1 = *(const v8s*)(kc + (ni * 4 + 1) * 512);
            v8s kf2 = *(const v8s*)(kc + (ni * 4 + 2) * 512);
            v8s kf3 = *(const v8s*)(kc + (ni * 4 + 3) * 512);
            st[0][ni] = __builtin_amdgcn_mfma_f32_16x16x32_bf16(kf0, qf[0][0], st[0][ni], 0, 0, 0);
            st[1][ni] = __builtin_amdgcn_mfma_f32_16x16x32_bf16(kf0, qf[1][0], st[1][ni], 0, 0, 0);
            st[0][ni] = __builtin_amdgcn_mfma_f32_16x16x32_bf16(kf1, qf[0][1], st[0][ni], 0, 0, 0);
            st[1][ni] = __builtin_amdgcn_mfma_f32_16x16x32_bf16(kf1, qf[1][1], st[1][ni], 0, 0, 0);
            st[0][ni] = __builtin_amdgcn_mfma_f32_16x16x32_bf16(kf2, qf[0][2], st[0][ni], 0, 0, 0);
            st[1][ni] = __builtin_amdgcn_mfma_f32_16x16x32_bf16(kf2, qf[1][2], st[1][ni], 0, 0, 0);
            st[0][ni] = __builtin_amdgcn_mfma_f32_16x16x32_bf16(kf3, qf[0][3], st[0][ni], 0, 0, 0);
            st[1][ni] = __builtin_amdgcn_mfma_f32_16x16x32_bf16(kf3, qf[1][3], st[1][ni], 0, 0, 0);
        }

        // softmax: lane holds qrow=ln, key = ni*16 + qd*4 + r -> b64 P writes
        const bool needMask = (kt * 64 + 63 > wrow0);
        for (int qg = 0; qg < 2; ++qg) {
            int prow = wv * 32 + qg * 16 + ln;
            int qrow_g = wrow0 + qg * 16 + ln;
            for (int ni = 0; ni < 4; ++ni) {
                union { short s[4]; uint64_t u; } pk;
                for (int r = 0; r < 4; ++r) {
                    float p = exp2f(st[qg][ni][r] * sc);
                    int kg = kt * 64 + ni * 16 + qd * 4 + r;
                    if (needMask && kg > qrow_g) p = 0.f;
                    rs[qg] += p;
                    pk.s[r] = f2bf(p);
                }
                *(uint64_t*)(&sP[prow * 72 + ni * 16 + qd * 4]) = pk.u;
            }
        }

        // P fragments (same-wave sP rows; lgkmcnt orders write->read)
        v8s pf[2][2];
#pragma unroll
        for (int qg = 0; qg < 2; ++qg)
#pragma unroll
            for (int kk2 = 0; kk2 < 2; ++kk2)
                pf[qg][kk2] = *(const v8s*)&sP[(wv * 32 + qg * 16 + ln) * 72 + kk2 * 32 + qd * 8];

        // O^T += : A = V fragments (direct), B = P fragments
#pragma unroll
        for (int og = 0; og < 4; ++og) {
            v8s vf00 = *(const v8s*)(vc + ((og * 2 + 0) * 2 + 0) * 512);
            v8s vf01 = *(const v8s*)(vc + ((og * 2 + 0) * 2 + 1) * 512);
            v8s vf10 = *(const v8s*)(vc + ((og * 2 + 1) * 2 + 0) * 512);
            v8s vf11 = *(const v8s*)(vc + ((og * 2 + 1) * 2 + 1) * 512);
            o[0][og * 2]     = __builtin_amdgcn_mfma_f32_16x16x32_bf16(vf00, pf[0][0], o[0][og * 2], 0, 0, 0);
            o[0][og * 2]     = __builtin_amdgcn_mfma_f32_16x16x32_bf16(vf01, pf[0][1], o[0][og * 2], 0, 0, 0);
            o[1][og * 2]     = __builtin_amdgcn_mfma_f32_16x16x32_bf16(vf00, pf[1][0], o[1][og * 2], 0, 0, 0);
            o[1][og * 2]     = __builtin_amdgcn_mfma_f32_16x16x32_bf16(vf01, pf[1][1], o[1][og * 2], 0, 0, 0);
            o[0][og * 2 + 1] = __builtin_amdgcn_mfma_f32_16x16x32_bf16(vf10, pf[0][0], o[0][og * 2 + 1], 0, 0, 0);
            o[0][og * 2 + 1] = __builtin_amdgcn_mfma_f32_16x16x32_bf16(vf11, pf[0][1], o[0][og * 2 + 1], 0, 0, 0);
            o[1][og * 2 + 1] = __builtin_amdgcn_mfma_f32_16x16x32_bf16(vf10, pf[1][0], o[1][og * 2 + 1], 0, 0, 0);
            o[1][og * 2 + 1] = __builtin_amdgcn_mfma_f32_16x16x32_bf16(vf11, pf[1][1], o[1][og * 2 + 1], 0, 0, 0);
        }
    }

    // row sums: reduce across qd lanes (xor 16, 32)
    float lsum[2];
    for (int qg = 0; qg < 2; ++qg) {
        float v = rs[qg];
        v += __shfl_xor(v, 16);
        v += __shfl_xor(v, 32);
        lsum[qg] = v;
    }

    short* pob = po + (size_t)bid * 128 * 128;
    for (int qg = 0; qg < 2; ++qg)
        for (int oni = 0; oni < 8; ++oni) {
            union { short s[4]; uint2 u; } pk;
            for (int r = 0; r < 4; ++r) pk.s[r] = f2bf(o[qg][oni][r]);
            *(uint2*)(&pob[(((qg * 8 + oni) * 4 + wv) * 64 + lane) * 4]) = pk.u;
        }
    if (lane < 16)
        for (int qg = 0; qg < 2; ++qg)
            pl[bid * 128 + wv * 32 + qg * 16 + lane] = lsum[qg];
}

// ---------------- kernel 4: combine splits ----------------
__global__ __launch_bounds__(256)
void combine_kernel(const short* __restrict__ po, const float* __restrict__ pl,
                    float* __restrict__ out) {
    const int bid = blockIdx.x;          // 512: b<<6 | qt2<<2 | qh<<1 | dh
    const int dh  = bid & 1;
    const int qh  = (bid >> 1) & 1;
    const int qt2 = (bid >> 2) & 15;
    const int b   = bid >> 6;
    const int cum = qt2 * (qt2 + 1) / 2;   // sum_{j<qt2} (j+1)
    const int S   = qt2 + 1;

    const int t = threadIdx.x;
    const int wv = t >> 6, lane = t & 63, ln = lane & 15, qd = lane >> 4;

    float l = 0.f;
    float accv[4][4] = {};

    for (int si = 0; si < S; ++si) {
        int slot = (cum + si) * 8 + b;
        l += pl[slot * 128 + wv * 32 + qh * 16 + ln];
        const short* pob = po + (size_t)slot * 16384;
        for (int oi = 0; oi < 4; ++oi) {
            int oni = dh * 4 + oi;
            union { short s[4]; uint2 u; } pk;
            pk.u = *(const uint2*)(&pob[(((qh * 8 + oni) * 4 + wv) * 64 + lane) * 4]);
            for (int r = 0; r < 4; ++r) accv[oi][r] += bf2f(pk.s[r]);
        }
    }
    float inv = 1.f / l;
    // lane holds qrow = ln, d = (dh*4+oi)*16 + qd*4 + r
    float* ob = out + ((size_t)(b * T_SEQ) + qt2 * 128 + wv * 32 + qh * 16 + ln) * HEAD;
    for (int oi = 0; oi < 4; ++oi) {
        float4 o4 = make_float4(accv[oi][0] * inv, accv[oi][1] * inv,
                                accv[oi][2] * inv, accv[oi][3] * inv);
        *(float4*)(ob + (dh * 4 + oi) * 16 + qd * 4) = o4;
    }
}

extern "C" void kernel_launch(void* const* d_in, const int* in_sizes, int n_in,
                              void* d_out, int out_size, void* d_ws, size_t ws_size,
                              hipStream_t stream) {
    const float* x  = (const float*)d_in[0];
    const float* Wk = (const float*)d_in[1];
    const float* Wq = (const float*)d_in[2];
    const float* Wv = (const float*)d_in[3];
    float* out = (float*)d_out;

    char* ws = (char*)d_ws;
    short* wpk = (short*)ws;                              // 768 KB   (dead after qkv)
    short* xpk = (short*)(ws + 0x100000u);                // 32 MB    (dead after qkv)
    short* po  = (short*)ws;                              // 34 MB (overlaps wpk/xpk; live after qkv)
    float* pl  = (float*)(ws + 0x2200000u);               // 1088*128 f32
    short* qb  = (short*)(ws + 0x2300000u);               // 4 MB
    short* kpk = (short*)(ws + 0x2700000u);               // 4 MB, fragment-packed K
    short* vpk = (short*)(ws + 0x2B00000u);               // 4 MB, fragment-packed V^T
    short* qkv = qb;

    pack_kernel<<<2560, 256, 0, stream>>>(x, Wq, Wk, Wv, xpk, wpk);
    qkv_gemm<<<768, 256, 0, stream>>>(xpk, wpk, qkv, kpk, vpk);
    attn_kernel<<<BATCH * BPB, 256, 0, stream>>>(qb, kpk, vpk, po, pl);
    combine_kernel<<<512, 256, 0, stream>>>(po, pl, out);
}

// Round 10
// 164.360 us; speedup vs baseline: 1.0424x; 1.0424x over previous
//
#include <hip/hip_runtime.h>
#include <hip/hip_bf16.h>
#include <stdint.h>

typedef short v8s __attribute__((ext_vector_type(8)));
typedef float v4f __attribute__((ext_vector_type(4)));
typedef float v16f __attribute__((ext_vector_type(16)));

#define N_EMBD 1024
#define HEAD 128
#define TOKENS 16384   // 8*2048
#define T_SEQ 2048
#define BATCH 8
#define BPB 96         // attn blocks/batch: sum_{qt2=0}^{15} ceil((2qt2+2)/3)

__device__ __forceinline__ short f2bf(float f) {
    union { float f; uint32_t u; } c; c.f = f;
    uint32_t u = c.u;
    uint32_t r = (u + 0x7fffu + ((u >> 16) & 1u)) >> 16;
    return (short)r;
}

__device__ __forceinline__ float bf2f(short s) {
    union { uint32_t u; float f; } c; c.u = ((uint32_t)(uint16_t)s) << 16;
    return c.f;
}

// ---------------- kernel 1: fused pack (x -> xpk, W -> wpk) ----------------
// blocks 0..1023:  x -> bf16 in MFMA A-fragment order (LDS-staged, both sides
//                  coalesced). chunk (rb,kb) = 64 lanes x 8 shorts;
//                  tok = rb*32+(l&31), k = kb*16+(l>>5)*8+j.
// blocks 1024..2559: W -> bf16 in B-fragment order.
__global__ __launch_bounds__(256)
void pack_kernel(const float* __restrict__ x,
                 const float* __restrict__ Wq, const float* __restrict__ Wk,
                 const float* __restrict__ Wv,
                 short* __restrict__ xpk, short* __restrict__ wpk) {
    const int blk = blockIdx.x;
    const int t   = threadIdx.x;
    if (blk < 1024) {
        const int rb = blk >> 1;          // 0..511
        const int kh = blk & 1;           // k-half (512 k each)
        __shared__ short sX[32 * 520];    // [tok][k_local], pad to 520

        for (int it = 0; it < 8; ++it) {
            int idx = it * 256 + t;       // 2048 = 32 tok * 64 octets
            int tok = idx >> 6, ko = idx & 63;
            const float* src = x + (size_t)(rb * 32 + tok) * 1024 + kh * 512 + ko * 8;
            float4 lo = *(const float4*)(src);
            float4 hi = *(const float4*)(src + 4);
            union { short s[8]; uint4 u; } p;
            p.s[0] = f2bf(lo.x); p.s[1] = f2bf(lo.y); p.s[2] = f2bf(lo.z); p.s[3] = f2bf(lo.w);
            p.s[4] = f2bf(hi.x); p.s[5] = f2bf(hi.y); p.s[6] = f2bf(hi.z); p.s[7] = f2bf(hi.w);
            *(uint4*)(&sX[tok * 520 + ko * 8]) = p.u;
        }
        __syncthreads();

        for (int it = 0; it < 8; ++it) {
            int kb_loc = it * 4 + (t >> 6);   // 0..31
            int l = t & 63;
            uint4 d = *(const uint4*)(&sX[(l & 31) * 520 + kb_loc * 16 + (l >> 5) * 8]);
            int kb = kh * 32 + kb_loc;
            *(uint4*)(&xpk[(((size_t)rb * 64 + kb) * 64 + l) * 8]) = d;
        }
    } else {
        int tid = (blk - 1024) * 256 + t;
        int w   = tid >> 17;
        int rem = tid & 131071;               // c*128 + h
        int c = rem >> 7, h = rem & 127;
        const float* src = (w == 0) ? Wq : ((w == 1) ? Wk : Wv);
        int cb = h >> 5, kb = c >> 4;
        int l  = (h & 31) | (((c >> 3) & 1) << 5);
        wpk[((((w * 4 + cb) * 64) + kb) * 64 + l) * 8 + (c & 7)] = f2bf(src[rem]);
    }
}

// ---------------- kernel 2: QKV GEMM, packed-fragment streaming ----------------
// Main loop: zero LDS / zero barriers / depth-2 named-register prefetch.
// Epilogues: w==0 -> qb rows; w==1 -> K in attn-A-fragment chunks (kpk);
// w==2 -> V^T in attn-A-fragment chunks (vpk).
__global__ __launch_bounds__(256)
void qkv_gemm(const short* __restrict__ xpk, const short* __restrict__ wpk,
              short* __restrict__ qkv, short* __restrict__ kpk,
              short* __restrict__ vpk) {
    const int bid = blockIdx.x;
    const int xcd = bid & 7, q = bid >> 3;
    const int mt  = xcd * 32 + q / 3;
    const int w   = q % 3;
    const int m0  = mt * 64;

    __shared__ short sT[128 * 72];   // epilogue staging (K path uses 64x136)

    const int t = threadIdx.x;
    const int lane = t & 63, wv = t >> 6;
    const int l31 = lane & 31, l1 = lane >> 5;
    const int wm = wv & 1, wn = wv >> 1;

    const int rb = mt * 2 + wm;                       // A row-block (32 rows)
    const short* ap  = xpk + (size_t)rb * 32768 + lane * 8;            // + kb*512
    const short* bp0 = wpk + (size_t)(w * 4 + 2 * wn) * 32768 + lane * 8;
    const short* bp1 = wpk + (size_t)(w * 4 + 2 * wn + 1) * 32768 + lane * 8;

    v16f acc[2];
    for (int i = 0; i < 16; ++i) { acc[0][i] = 0.f; acc[1][i] = 0.f; }

    v8s A0k0, A0k1, A1k0, A1k1;
    v8s B0k0n0, B0k0n1, B0k1n0, B0k1n1, B1k0n0, B1k0n1, B1k1n0, B1k1n1;

#define LOADSET0(IT) do { int o_ = (IT) * 1024;                                  \
        A0k0   = *(const v8s*)(ap  + o_);                                        \
        A0k1   = *(const v8s*)(ap  + o_ + 512);                                  \
        B0k0n0 = *(const v8s*)(bp0 + o_);                                        \
        B0k0n1 = *(const v8s*)(bp1 + o_);                                        \
        B0k1n0 = *(const v8s*)(bp0 + o_ + 512);                                  \
        B0k1n1 = *(const v8s*)(bp1 + o_ + 512);                                  \
    } while (0)

#define LOADSET1(IT) do { int o_ = (IT) * 1024;                                  \
        A1k0   = *(const v8s*)(ap  + o_);                                        \
        A1k1   = *(const v8s*)(ap  + o_ + 512);                                  \
        B1k0n0 = *(const v8s*)(bp0 + o_);                                        \
        B1k0n1 = *(const v8s*)(bp1 + o_);                                        \
        B1k1n0 = *(const v8s*)(bp0 + o_ + 512);                                  \
        B1k1n1 = *(const v8s*)(bp1 + o_ + 512);                                  \
    } while (0)

#define COMPUTE0() do {                                                          \
        acc[0] = __builtin_amdgcn_mfma_f32_32x32x16_bf16(A0k0, B0k0n0, acc[0], 0, 0, 0); \
        acc[1] = __builtin_amdgcn_mfma_f32_32x32x16_bf16(A0k0, B0k0n1, acc[1], 0, 0, 0); \
        acc[0] = __builtin_amdgcn_mfma_f32_32x32x16_bf16(A0k1, B0k1n0, acc[0], 0, 0, 0); \
        acc[1] = __builtin_amdgcn_mfma_f32_32x32x16_bf16(A0k1, B0k1n1, acc[1], 0, 0, 0); \
    } while (0)

#define COMPUTE1() do {                                                          \
        acc[0] = __builtin_amdgcn_mfma_f32_32x32x16_bf16(A1k0, B1k0n0, acc[0], 0, 0, 0); \
        acc[1] = __builtin_amdgcn_mfma_f32_32x32x16_bf16(A1k0, B1k0n1, acc[1], 0, 0, 0); \
        acc[0] = __builtin_amdgcn_mfma_f32_32x32x16_bf16(A1k1, B1k1n0, acc[0], 0, 0, 0); \
        acc[1] = __builtin_amdgcn_mfma_f32_32x32x16_bf16(A1k1, B1k1n1, acc[1], 0, 0, 0); \
    } while (0)

    LOADSET0(0);
    LOADSET1(1);
    for (int it = 0; it < 32; it += 2) {
        COMPUTE0();
        if (it + 2 < 32) LOADSET0(it + 2);
        COMPUTE1();
        if (it + 3 < 32) LOADSET1(it + 3);
    }

#undef LOADSET0
#undef LOADSET1
#undef COMPUTE0
#undef COMPUTE1

    // epilogues. 32x32 C-layout: col = lane&31, row m = (reg&3) + 8*(reg>>2) + 4*l1
    const int b_  = m0 >> 11;
    const int kt_ = (m0 >> 6) & 31;
    if (w == 0) {
        for (int ni = 0; ni < 2; ++ni) {
            int col = wn * 64 + ni * 32 + l31;
            for (int reg = 0; reg < 16; ++reg) {
                int m = (reg & 3) + 8 * (reg >> 2) + 4 * l1;
                qkv[(size_t)(m0 + wm * 32 + m) * HEAD + col] = f2bf(acc[ni][reg]);
            }
        }
    } else if (w == 1) {
        // stage [token][head] stride 136, then emit attn A-fragment chunks
        for (int ni = 0; ni < 2; ++ni) {
            int col = wn * 64 + ni * 32 + l31;
            for (int reg = 0; reg < 16; ++reg) {
                int m = (reg & 3) + 8 * (reg >> 2) + 4 * l1;
                sT[(wm * 32 + m) * 136 + col] = f2bf(acc[ni][reg]);
            }
        }
        __syncthreads();
        short* kdst = kpk + ((size_t)(b_ * 32 + kt_) * 16) * 512;
        for (int it = 0; it < 4; ++it) {
            int c = it * 256 + t;
            int chunk = c >> 6, l = c & 63;        // chunk = ni*4 + ks
            int ni2 = chunk >> 2, ks = chunk & 3;
            uint4 d = *(const uint4*)(&sT[(ni2 * 16 + (l & 15)) * 136 + ks * 32 + (l >> 4) * 8]);
            *(uint4*)(&kdst[chunk * 512 + l * 8]) = d;
        }
    } else {
        // stage V^T [d][token] stride 72, then emit attn A-fragment chunks
        for (int ni = 0; ni < 2; ++ni) {
            int col = wn * 64 + ni * 32 + l31;
            for (int g = 0; g < 4; ++g) {
                union { short s[4]; uint64_t u; } pk;
                for (int r = 0; r < 4; ++r) pk.s[r] = f2bf(acc[ni][g * 4 + r]);
                *(uint64_t*)(&sT[col * 72 + wm * 32 + 8 * g + 4 * l1]) = pk.u;
            }
        }
        __syncthreads();
        short* vdst = vpk + ((size_t)(b_ * 32 + kt_) * 16) * 512;
        for (int it = 0; it < 4; ++it) {
            int c = it * 256 + t;
            int chunk = c >> 6, l = c & 63;        // chunk = oni*2 + kk2
            int oni = chunk >> 1, kk2 = chunk & 1;
            uint4 d = *(const uint4*)(&sT[(oni * 16 + (l & 15)) * 72 + kk2 * 32 + (l >> 4) * 8]);
            *(uint4*)(&vdst[chunk * 512 + l * 8]) = d;
        }
    }
}

// ---------------- kernel 3: flash attention, barrier-free fragment streaming ----
// S^T = K·Q^T (A=K frags direct from kpk), O^T += V^T·P (A=V frags direct from
// vpk). Zero s_barrier: K/V fragment loads are coalesced global->VGPR (1KB per
// wave-load); only P goes through LDS, written+read by the SAME wave (lgkmcnt
// ordering). Masked waves break out. Flat load order (compiler schedules).
__global__ __launch_bounds__(256)
void attn_kernel(const short* __restrict__ qb, const short* __restrict__ kpk,
                 const short* __restrict__ vpk, short* __restrict__ po,
                 float* __restrict__ pl) {
    const int bid = blockIdx.x;
    const int b  = bid & 7;
    const int r0 = bid >> 3;        // 0..95
    int qt2 = 0, c0 = 0;
    for (;;) { int sz = (2 * qt2 + 4) / 3; if (r0 < c0 + sz) break; c0 += sz; ++qt2; }
    const int s = r0 - c0;
    const int q0 = qt2 * 128;
    const int nkt = 2 * qt2 + 2;
    const int kt0 = s * 3;
    const int kt1 = (kt0 + 3 < nkt) ? (kt0 + 3) : nkt;

    __shared__ short sP[128 * 72];    // P [qrow][key], stride 72 (per-wave rows)

    const int t = threadIdx.x;
    const int wv = t >> 6, lane = t & 63, ln = lane & 15, qd = lane >> 4;
    const int wrow0 = q0 + wv * 32;

    v8s qf[2][4];
    for (int qg = 0; qg < 2; ++qg) {
        const short* qrow = qb + ((size_t)(b * T_SEQ + wrow0 + qg * 16 + ln)) * HEAD;
        for (int ks = 0; ks < 4; ++ks)
            qf[qg][ks] = *(const v8s*)(qrow + ks * 32 + qd * 8);
    }

    v4f o[2][8] = {};
    float rs[2] = {0.f, 0.f};
    const float sc = 1.4426950408889634f / 11.313708498984761f;  // log2e / sqrt(128)

    const short* kbB = kpk + ((size_t)b * 32 * 16) * 512 + lane * 8;
    const short* vbB = vpk + ((size_t)b * 32 * 16) * 512 + lane * 8;

    for (int kt = kt0; kt < kt1; ++kt) {
        if (kt * 64 >= wrow0 + 32) break;   // fully masked from here on
        const short* kc = kbB + (size_t)kt * 8192;
        const short* vc = vbB + (size_t)kt * 8192;

        // S^T: A = K fragments (direct), B = Q fragments
        v4f st[2][4] = {};
#pragma unroll
        for (int ni = 0; ni < 4; ++ni) {
            v8s kf0 = *(const v8s*)(kc + (ni * 4 + 0) * 512);
            v8s kf1 = *(const v8s*)(kc + (ni * 4 + 1) * 512);
            v8s kf2 = *(const v8s*)(kc + (ni * 4 + 2) * 512);
            v8s kf3 = *(const v8s*)(kc + (ni * 4 + 3) * 512);
            st[0][ni] = __builtin_amdgcn_mfma_f32_16x16x32_bf16(kf0, qf[0][0], st[0][ni], 0, 0, 0);
            st[1][ni] = __builtin_amdgcn_mfma_f32_16x16x32_bf16(kf0, qf[1][0], st[1][ni], 0, 0, 0);
            st[0][ni] = __builtin_amdgcn_mfma_f32_16x16x32_bf16(kf1, qf[0][1], st[0][ni], 0, 0, 0);
            st[1][ni] = __builtin_amdgcn_mfma_f32_16x16x32_bf16(kf1, qf[1][1], st[1][ni], 0, 0, 0);
            st[0][ni] = __builtin_amdgcn_mfma_f32_16x16x32_bf16(kf2, qf[0][2], st[0][ni], 0, 0, 0);
            st[1][ni] = __builtin_amdgcn_mfma_f32_16x16x32_bf16(kf2, qf[1][2], st[1][ni], 0, 0, 0);
            st[0][ni] = __builtin_amdgcn_mfma_f32_16x16x32_bf16(kf3, qf[0][3], st[0][ni], 0, 0, 0);
            st[1][ni] = __builtin_amdgcn_mfma_f32_16x16x32_bf16(kf3, qf[1][3], st[1][ni], 0, 0, 0);
        }

        // softmax: lane holds qrow=ln, key = ni*16 + qd*4 + r -> b64 P writes
        const bool needMask = (kt * 64 + 63 > wrow0);
        for (int qg = 0; qg < 2; ++qg) {
            int prow = wv * 32 + qg * 16 + ln;
            int qrow_g = wrow0 + qg * 16 + ln;
            for (int ni = 0; ni < 4; ++ni) {
                union { short s[4]; uint64_t u; } pk;
                for (int r = 0; r < 4; ++r) {
                    float p = exp2f(st[qg][ni][r] * sc);
                    int kg = kt * 64 + ni * 16 + qd * 4 + r;
                    if (needMask && kg > qrow_g) p = 0.f;
                    rs[qg] += p;
                    pk.s[r] = f2bf(p);
                }
                *(uint64_t*)(&sP[prow * 72 + ni * 16 + qd * 4]) = pk.u;
            }
        }

        // P fragments (same-wave sP rows; lgkmcnt orders write->read)
        v8s pf[2][2];
#pragma unroll
        for (int qg = 0; qg < 2; ++qg)
#pragma unroll
            for (int kk2 = 0; kk2 < 2; ++kk2)
                pf[qg][kk2] = *(const v8s*)&sP[(wv * 32 + qg * 16 + ln) * 72 + kk2 * 32 + qd * 8];

        // O^T += : A = V fragments (direct), B = P fragments
#pragma unroll
        for (int og = 0; og < 4; ++og) {
            v8s vf00 = *(const v8s*)(vc + ((og * 2 + 0) * 2 + 0) * 512);
            v8s vf01 = *(const v8s*)(vc + ((og * 2 + 0) * 2 + 1) * 512);
            v8s vf10 = *(const v8s*)(vc + ((og * 2 + 1) * 2 + 0) * 512);
            v8s vf11 = *(const v8s*)(vc + ((og * 2 + 1) * 2 + 1) * 512);
            o[0][og * 2]     = __builtin_amdgcn_mfma_f32_16x16x32_bf16(vf00, pf[0][0], o[0][og * 2], 0, 0, 0);
            o[0][og * 2]     = __builtin_amdgcn_mfma_f32_16x16x32_bf16(vf01, pf[0][1], o[0][og * 2], 0, 0, 0);
            o[1][og * 2]     = __builtin_amdgcn_mfma_f32_16x16x32_bf16(vf00, pf[1][0], o[1][og * 2], 0, 0, 0);
            o[1][og * 2]     = __builtin_amdgcn_mfma_f32_16x16x32_bf16(vf01, pf[1][1], o[1][og * 2], 0, 0, 0);
            o[0][og * 2 + 1] = __builtin_amdgcn_mfma_f32_16x16x32_bf16(vf10, pf[0][0], o[0][og * 2 + 1], 0, 0, 0);
            o[0][og * 2 + 1] = __builtin_amdgcn_mfma_f32_16x16x32_bf16(vf11, pf[0][1], o[0][og * 2 + 1], 0, 0, 0);
            o[1][og * 2 + 1] = __builtin_amdgcn_mfma_f32_16x16x32_bf16(vf10, pf[1][0], o[1][og * 2 + 1], 0, 0, 0);
            o[1][og * 2 + 1] = __builtin_amdgcn_mfma_f32_16x16x32_bf16(vf11, pf[1][1], o[1][og * 2 + 1], 0, 0, 0);
        }
    }

    // row sums: reduce across qd lanes (xor 16, 32)
    float lsum[2];
    for (int qg = 0; qg < 2; ++qg) {
        float v = rs[qg];
        v += __shfl_xor(v, 16);
        v += __shfl_xor(v, 32);
        lsum[qg] = v;
    }

    short* pob = po + (size_t)bid * 128 * 128;
    for (int qg = 0; qg < 2; ++qg)
        for (int oni = 0; oni < 8; ++oni) {
            union { short s[4]; uint2 u; } pk;
            for (int r = 0; r < 4; ++r) pk.s[r] = f2bf(o[qg][oni][r]);
            *(uint2*)(&pob[(((qg * 8 + oni) * 4 + wv) * 64 + lane) * 4]) = pk.u;
        }
    if (lane < 16)
        for (int qg = 0; qg < 2; ++qg)
            pl[bid * 128 + wv * 32 + qg * 16 + lane] = lsum[qg];
}

// ---------------- kernel 4: combine splits ----------------
__global__ __launch_bounds__(256)
void combine_kernel(const short* __restrict__ po, const float* __restrict__ pl,
                    float* __restrict__ out) {
    const int bid = blockIdx.x;          // 512: b<<6 | qt2<<2 | qh<<1 | dh
    const int dh  = bid & 1;
    const int qh  = (bid >> 1) & 1;
    const int qt2 = (bid >> 2) & 15;
    const int b   = bid >> 6;
    int cum = 0;
    for (int j = 0; j < qt2; ++j) cum += (2 * j + 4) / 3;
    const int S = (2 * qt2 + 4) / 3;

    const int t = threadIdx.x;
    const int wv = t >> 6, lane = t & 63, ln = lane & 15, qd = lane >> 4;

    float l = 0.f;
    float accv[4][4] = {};

    for (int si = 0; si < S; ++si) {
        int slot = (cum + si) * 8 + b;
        l += pl[slot * 128 + wv * 32 + qh * 16 + ln];
        const short* pob = po + (size_t)slot * 16384;
        for (int oi = 0; oi < 4; ++oi) {
            int oni = dh * 4 + oi;
            union { short s[4]; uint2 u; } pk;
            pk.u = *(const uint2*)(&pob[(((qh * 8 + oni) * 4 + wv) * 64 + lane) * 4]);
            for (int r = 0; r < 4; ++r) accv[oi][r] += bf2f(pk.s[r]);
        }
    }
    float inv = 1.f / l;
    // lane holds qrow = ln, d = (dh*4+oi)*16 + qd*4 + r
    float* ob = out + ((size_t)(b * T_SEQ) + qt2 * 128 + wv * 32 + qh * 16 + ln) * HEAD;
    for (int oi = 0; oi < 4; ++oi) {
        float4 o4 = make_float4(accv[oi][0] * inv, accv[oi][1] * inv,
                                accv[oi][2] * inv, accv[oi][3] * inv);
        *(float4*)(ob + (dh * 4 + oi) * 16 + qd * 4) = o4;
    }
}

extern "C" void kernel_launch(void* const* d_in, const int* in_sizes, int n_in,
                              void* d_out, int out_size, void* d_ws, size_t ws_size,
                              hipStream_t stream) {
    const float* x  = (const float*)d_in[0];
    const float* Wk = (const float*)d_in[1];
    const float* Wq = (const float*)d_in[2];
    const float* Wv = (const float*)d_in[3];
    float* out = (float*)d_out;

    char* ws = (char*)d_ws;
    short* wpk = (short*)ws;                              // 768 KB   (dead after qkv)
    short* xpk = (short*)(ws + 0x100000u);                // 32 MB    (dead after qkv)
    short* qb  = (short*)(ws + 0x2100000u);               // 4 MB
    short* kpk = (short*)(ws + 0x2500000u);               // 4 MB, fragment-packed K
    short* vpk = (short*)(ws + 0x2900000u);               // 4 MB, fragment-packed V^T
    short* po  = (short*)ws;                              // 24 MB (overlaps wpk/xpk)
    float* pl  = (float*)(ws + 0x1800000u);               // 768*128 f32
    short* qkv = qb;

    pack_kernel<<<2560, 256, 0, stream>>>(x, Wq, Wk, Wv, xpk, wpk);
    qkv_gemm<<<768, 256, 0, stream>>>(xpk, wpk, qkv, kpk, vpk);
    attn_kernel<<<BATCH * BPB, 256, 0, stream>>>(qb, kpk, vpk, po, pl);
    combine_kernel<<<512, 256, 0, stream>>>(po, pl, out);
}